// Round 5
// baseline (133.094 us; speedup 1.0000x reference)
//
#include <hip/hip_runtime.h>

// RewardTripletLoss: sim/gram GEMMs (bf16 MFMA) + per-row loss + FastAP rewards.
// R8: precompute label-match bitmasks (PL/NL/PG, 2MB each) in a tiny kernel.
// lossap: 3 u16 mask loads replace 8 int4 label loads/thread (-50% VMEM instrs,
// -128MB L2 broadcast) and all per-elem label compares / diag checks / npos
// counting (popcount). Diag's histA weight removed via one-thread atomicSub
// (u32 adds commute -> safe pre-barrier). Thread now owns 16 contiguous elems.

#define N_ROWS 4096
#define DIM 128
#define TILE 128
#define L_BINS 1601

typedef __bf16 bf16x8 __attribute__((ext_vector_type(8)));
typedef float f32x4 __attribute__((ext_vector_type(4)));

__device__ __forceinline__ unsigned short f32_to_bf16(float f) {
    unsigned int u = __float_as_uint(f);
    u = (u + 0x7FFFu + ((u >> 16) & 1u)) >> 16;
    return (unsigned short)u;
}

__device__ __forceinline__ float bf16_lo(unsigned int u) {
    return __uint_as_float(u << 16);
}
__device__ __forceinline__ float bf16_hi(unsigned int u) {
    return __uint_as_float(u & 0xFFFF0000u);
}

__device__ __forceinline__ void unpack8(uint4 pk, float* s) {
    s[0] = bf16_lo(pk.x); s[1] = bf16_hi(pk.x);
    s[2] = bf16_lo(pk.y); s[3] = bf16_hi(pk.y);
    s[4] = bf16_lo(pk.z); s[5] = bf16_hi(pk.z);
    s[6] = bf16_lo(pk.w); s[7] = bf16_hi(pk.w);
}

// Async global->LDS, 16B per lane. LDS dest is wave-uniform base + lane*16.
__device__ __forceinline__ void async_copy16(const void* g, void* l) {
    __builtin_amdgcn_global_load_lds(
        (const __attribute__((address_space(1))) unsigned int*)g,
        (__attribute__((address_space(3))) unsigned int*)l, 16, 0, 0);
}

// Label-match bitmasks, one byte per 8 columns:
//   PL[i*512+b] bit k: trow[8b+k]==tcol[i] && j!=i   (loss positives)
//   NL[i*512+b] bit k: trow[8b+k]!=tcol[i]           (loss negatives)
//   PG[i*512+b] bit k: rlab[8b+k]==rlab[i] && j!=i   (fastap positives)
// Label arrays are 16KB -> L1-hot; outputs 6MB total.
__global__ __launch_bounds__(256) void mask_kernel(const int* __restrict__ tcol,
                                                   const int* __restrict__ trow,
                                                   const int* __restrict__ rlab,
                                                   unsigned char* __restrict__ PL,
                                                   unsigned char* __restrict__ NL,
                                                   unsigned char* __restrict__ PG) {
    const int total = N_ROWS * (N_ROWS / 8);  // 2M byte-triples
    const int4* trv = (const int4*)trow;
    const int4* rlv = (const int4*)rlab;
    for (int idx = blockIdx.x * 256 + threadIdx.x; idx < total; idx += gridDim.x * 256) {
        int i = idx >> 9;   // row
        int b = idx & 511;  // byte (8-column chunk)
        int j0 = b << 3;
        int4 t0 = trv[b * 2], t1 = trv[b * 2 + 1];
        int4 r0 = rlv[b * 2], r1 = rlv[b * 2 + 1];
        int mt = tcol[i];
        int mr = rlab[i];
        int tj[8] = {t0.x, t0.y, t0.z, t0.w, t1.x, t1.y, t1.z, t1.w};
        int rj[8] = {r0.x, r0.y, r0.z, r0.w, r1.x, r1.y, r1.z, r1.w};
        unsigned int pl = 0, nl = 0, pg = 0;
#pragma unroll
        for (int k = 0; k < 8; ++k) {
            int j = j0 + k;
            bool sm = (tj[k] == mt);
            pl |= ((unsigned int)(sm && j != i)) << k;
            nl |= ((unsigned int)(!sm)) << k;
            pg |= ((unsigned int)((rj[k] == mr) && j != i)) << k;
        }
        PL[idx] = (unsigned char)pl;
        NL[idx] = (unsigned char)nl;
        PG[idx] = (unsigned char)pg;
    }
}

// Both f32->bf16 conversions in one launch.
__global__ __launch_bounds__(256) void cvt2_kernel(const float4* __restrict__ a,
                                                   const float4* __restrict__ b,
                                                   ushort4* __restrict__ oa,
                                                   ushort4* __restrict__ ob,
                                                   int nvec) {
    for (int idx = blockIdx.x * 256 + threadIdx.x; idx < 2 * nvec; idx += gridDim.x * 256) {
        bool second = idx >= nvec;
        int k = second ? idx - nvec : idx;
        float4 v = second ? b[k] : a[k];
        ushort4 o;
        o.x = f32_to_bf16(v.x); o.y = f32_to_bf16(v.y);
        o.z = f32_to_bf16(v.z); o.w = f32_to_bf16(v.w);
        if (second) ob[k] = o; else oa[k] = o;
    }
}

// C[i][j] = sum_k A[i][k]*Bz[j][k]. Grid (32,32,2): z=0 -> B0->C0 (sim), z=1 -> B1->C1 (gram).
__global__ __launch_bounds__(256) void gemm_tile_kernel(const unsigned short* __restrict__ A,
                                                        const unsigned short* __restrict__ B0,
                                                        const unsigned short* __restrict__ B1,
                                                        unsigned short* __restrict__ C0,
                                                        unsigned short* __restrict__ C1,
                                                        int N) {
    __shared__ unsigned short As[TILE * DIM];  // 32 KB (tile contiguous in global)
    __shared__ unsigned short Bs[TILE * DIM];  // 32 KB
    int w = threadIdx.x >> 6;
    int lane = threadIdx.x & 63;
    int tm = blockIdx.y, tn = blockIdx.x;
    const unsigned short* B = blockIdx.z ? B1 : B0;
    unsigned short* C = blockIdx.z ? C1 : C0;

    const char* ga = (const char*)(A + (size_t)tm * TILE * DIM);
    const char* gb = (const char*)(B + (size_t)tn * TILE * DIM);
#pragma unroll
    for (int it = 0; it < 8; ++it) {
        int off = (w * 8 + it) * 1024;  // wave-chunk of 1KB (64 lanes x 16B)
        async_copy16(ga + off + lane * 16, (char*)As + off);
        async_copy16(gb + off + lane * 16, (char*)Bs + off);
    }
    __syncthreads();

    int wm = (w & 1) * 64;
    int wn = (w >> 1) * 64;
    int quad = lane >> 4;
    int l15 = lane & 15;

    f32x4 acc[4][4] = {};
#pragma unroll
    for (int kk = 0; kk < 4; ++kk) {
        int kb = kk * 32 + quad * 8;
        bf16x8 af[4], bfr[4];
#pragma unroll
        for (int mi = 0; mi < 4; ++mi)
            af[mi] = *(const bf16x8*)&As[(wm + mi * 16 + l15) * DIM + kb];
#pragma unroll
        for (int ni = 0; ni < 4; ++ni)
            bfr[ni] = *(const bf16x8*)&Bs[(wn + ni * 16 + l15) * DIM + kb];
#pragma unroll
        for (int mi = 0; mi < 4; ++mi)
#pragma unroll
            for (int ni = 0; ni < 4; ++ni)
                acc[mi][ni] = __builtin_amdgcn_mfma_f32_16x16x32_bf16(af[mi], bfr[ni], acc[mi][ni], 0, 0, 0);
    }

#pragma unroll
    for (int mi = 0; mi < 4; ++mi) {
        int row0 = tm * TILE + wm + mi * 16 + quad * 4;
#pragma unroll
        for (int ni = 0; ni < 4; ++ni) {
            int col = tn * TILE + wn + ni * 16 + l15;
#pragma unroll
            for (int r = 0; r < 4; ++r)
                C[(size_t)(row0 + r) * N + col] = f32_to_bf16(acc[mi][ni][r]);
        }
    }
}

// Merged loss + FastAP: one block per row i. Thread t owns 16 contiguous
// elements j in [16t, 16t+16) (two uint4 loads each of sim/gram; one u16 per
// mask). No label loads, no per-elem label compares, npos = popcount.
// Diag excluded from PL/PG at mask-build; its histA weight removed by a
// one-thread atomicSub (u32 adds commute, pre-barrier safe).
__global__ __launch_bounds__(256) void lossap_kernel(const unsigned short* __restrict__ sim,
                                                     const unsigned short* __restrict__ gram,
                                                     const unsigned char* __restrict__ PL,
                                                     const unsigned char* __restrict__ NL,
                                                     const unsigned char* __restrict__ PG,
                                                     float* __restrict__ contrib,
                                                     int n) {
    __shared__ unsigned int histA[L_BINS];  // total weight (x65536 fixed point)
    __shared__ unsigned int histP[L_BINS];  // positive weight
    __shared__ unsigned long long wsum[4];
    __shared__ float pmx[4], nmx[4], lsum[4], apw[4];
    __shared__ int npw[4];
    int i = blockIdx.x;
    int t = threadIdx.x;
    int w = t >> 6, lane = t & 63;

    for (int b = t; b < L_BINS; b += 256) { histA[b] = 0u; histP[b] = 0u; }

    const uint4* simv = (const uint4*)(sim + (size_t)i * n);
    const uint4* grav = (const uint4*)(gram + (size_t)i * n);

    // Row data + masks for this thread's 16 elements.
    uint4 spk[2], gpk[2];
#pragma unroll
    for (int vv = 0; vv < 2; ++vv) {
        spk[vv] = simv[2 * t + vv];
        gpk[vv] = grav[2 * t + vv];
    }
    unsigned int pl16 = *(const unsigned short*)(PL + (size_t)i * 512 + 2 * t);
    unsigned int nl16 = *(const unsigned short*)(NL + (size_t)i * 512 + 2 * t);
    unsigned int pg16 = *(const unsigned short*)(PG + (size_t)i * 512 + 2 * t);
    __syncthreads();  // hist zeroed; row loads in flight

    // MERGED phase: sim maxima (VALU) + gram binning atomics (DS pipe).
    float pmax = -3e38f, nmax = -3e38f;
#pragma unroll
    for (int vv = 0; vv < 2; ++vv) {
        {
            float s[8];
            unpack8(spk[vv], s);
#pragma unroll
            for (int k = 0; k < 8; ++k) {
                int e = vv * 8 + k;
                if ((pl16 >> e) & 1u) pmax = fmaxf(pmax, s[k]);
                if ((nl16 >> e) & 1u) nmax = fmaxf(nmax, s[k]);
            }
        }
        {
            float g[8];
            unpack8(gpk[vv], g);
#pragma unroll
            for (int k = 0; k < 8; ++k) {
                int e = vv * 8 + k;
                float d2 = fminf(fmaxf(2.f - 2.f * g[k], 0.f), 4.f);
                float tt = d2 * 400.0f;  // / (4/1600)
                float fl = floorf(tt);
                int i0 = (int)fl;
                if (i0 > L_BINS - 1) i0 = L_BINS - 1;
                int i1 = i0 + 1;
                if (i1 > L_BINS - 1) i1 = L_BINS - 1;
                unsigned int w1 = (unsigned int)((tt - fl) * 65536.0f);
                unsigned int w0 = 65536u - w1;
                atomicAdd(&histA[i0], w0);
                atomicAdd(&histA[i1], w1);
                if ((pg16 >> e) & 1u) {
                    atomicAdd(&histP[i0], w0);
                    atomicAdd(&histP[i1], w1);
                }
            }
        }
    }
    int npos = __popc(pg16);

    // Remove the diagonal's histA contribution (added above as a normal elem).
    if (t == (i >> 4)) {
        int vv = (i >> 3) & 1, k = i & 7;
        float g[8];
        unpack8(gpk[vv], g);
        float d2 = fminf(fmaxf(2.f - 2.f * g[k], 0.f), 4.f);
        float tt = d2 * 400.0f;
        float fl = floorf(tt);
        int i0 = (int)fl;
        if (i0 > L_BINS - 1) i0 = L_BINS - 1;
        int i1 = i0 + 1;
        if (i1 > L_BINS - 1) i1 = L_BINS - 1;
        unsigned int w1 = (unsigned int)((tt - fl) * 65536.0f);
        unsigned int w0 = 65536u - w1;
        atomicSub(&histA[i0], w0);
        atomicSub(&histA[i1], w1);
    }

    // Wave maxima reduce (VALU, overlaps atomic drain).
#pragma unroll
    for (int off = 32; off > 0; off >>= 1) {
        pmax = fmaxf(pmax, __shfl_xor(pmax, off));
        nmax = fmaxf(nmax, __shfl_xor(nmax, off));
    }
    if (lane == 0) { pmx[w] = pmax; nmx[w] = nmax; }
    __syncthreads();  // atomics complete + wave maxima visible

    pmax = fmaxf(fmaxf(pmx[0], pmx[1]), fmaxf(pmx[2], pmx[3]));
    nmax = fmaxf(fmaxf(nmx[0], nmx[1]), fmaxf(nmx[2], nmx[3]));

    // Pass 2: loss sums from registers.
    float thr_n = nmax + 0.1f;               // pos selected when sim < neg_max + margin
    float thr_p = fmaxf(0.6f, pmax) - 0.1f;  // neg selected when sim > thr
    float pl = 0.f, nl = 0.f;
#pragma unroll
    for (int vv = 0; vv < 2; ++vv) {
        float s[8];
        unpack8(spk[vv], s);
#pragma unroll
        for (int k = 0; k < 8; ++k) {
            int e = vv * 8 + k;
            bool posf = (pl16 >> e) & 1u;
            bool negf = (nl16 >> e) & 1u;
            pl += (posf && s[k] < thr_n) ? 1.f - s[k] : 0.f;
            nl += (negf && s[k] > thr_p) ? s[k] : 0.f;
        }
    }
    float tot = pl + nl;
#pragma unroll
    for (int off = 32; off > 0; off >>= 1) tot += __shfl_xor(tot, off);

    // Chunked scan: 7 bins/thread; shuffle inclusive scan of thread totals.
    // Pack (pos<<32)|all so one u64 scan covers both cumsums (no carry between
    // halves: total all-weight per row = 4095*65536 < 2^32).
    const int CH = 7;
    int base = t * CH;
    unsigned long long lc[CH];
    unsigned long long run = 0ull;
#pragma unroll
    for (int k = 0; k < CH; ++k) {
        int idx = base + k;
        unsigned long long h = (idx < L_BINS)
            ? (((unsigned long long)histP[idx] << 32) | (unsigned long long)histA[idx])
            : 0ull;
        run += h;
        lc[k] = run;
    }
    unsigned long long tsum = run;
    unsigned long long sc = tsum;
#pragma unroll
    for (int off = 1; off < 64; off <<= 1) {
        unsigned long long v2 = __shfl_up(sc, off);
        if (lane >= off) sc += v2;
    }
    if (lane == 63) wsum[w] = sc;
    if (lane == 0) lsum[w] = tot;
    __syncthreads();
    unsigned long long woff = 0ull;
    for (int ww = 0; ww < w; ++ww) woff += wsum[ww];
    unsigned long long throff = woff + sc - tsum;  // exclusive offset for this thread

    float ap = 0.f;
#pragma unroll
    for (int k = 0; k < CH; ++k) {
        int idx = base + k;
        if (idx < L_BINS) {
            unsigned int hp = histP[idx];
            if (hp) {
                unsigned long long cum = lc[k] + throff;
                unsigned int Hp = (unsigned int)(cum >> 32);
                unsigned int Ha = (unsigned int)cum;
                ap += (float)hp * (float)Hp / (float)Ha;
            }
        }
    }
#pragma unroll
    for (int off = 32; off > 0; off >>= 1) {
        ap += __shfl_xor(ap, off);
        npos += __shfl_xor(npos, off);
    }
    if (lane == 0) { apw[w] = ap; npw[w] = npos; }
    __syncthreads();
    if (t == 0) {
        float loss_i = (pmax > -1e30f) ? (lsum[0] + lsum[1] + lsum[2] + lsum[3]) : 0.f;
        float A = apw[0] + apw[1] + apw[2] + apw[3];
        int np = npw[0] + npw[1] + npw[2] + npw[3];
        float reward = (np > 0) ? A * (1.0f / 65536.0f) / (float)np : 0.f;
        contrib[i] = loss_i * (1.f - reward);
    }
}

__global__ __launch_bounds__(256) void final_kernel(const float* __restrict__ contrib,
                                                    float* __restrict__ out, int n) {
    __shared__ float r[256];
    int t = threadIdx.x;
    float s = 0.f;
    for (int j = t; j < n; j += 256) s += contrib[j];
    r[t] = s;
    __syncthreads();
    for (int off = 128; off > 0; off >>= 1) {
        if (t < off) r[t] += r[t + off];
        __syncthreads();
    }
    if (t == 0) out[0] = r[0] / (float)n;
}

extern "C" void kernel_launch(void* const* d_in, const int* in_sizes, int n_in,
                              void* d_out, int out_size, void* d_ws, size_t ws_size,
                              hipStream_t stream) {
    const float* inputs_col = (const float*)d_in[0];
    const int* targets_col = (const int*)d_in[1];
    const float* inputs_row = (const float*)d_in[2];
    const int* targets_row = (const int*)d_in[3];
    const int* reward_labels = (const int*)d_in[4];
    float* out = (float*)d_out;

    const int n = N_ROWS, m = N_ROWS, d = DIM;
    char* ws = (char*)d_ws;
    const size_t MB = 1048576;
    unsigned short* simbuf = (unsigned short*)ws;                 // 32 MB
    unsigned short* grambuf = (unsigned short*)(ws + 32 * MB);    // 32 MB
    unsigned short* Abf = (unsigned short*)(ws + 64 * MB);        // 1 MB
    unsigned short* Rbf = (unsigned short*)(ws + 65 * MB);        // 1 MB
    float* contrib = (float*)(ws + 66 * MB);                      // 16 KB
    unsigned char* PL = (unsigned char*)(ws + 67 * MB);           // 2 MB
    unsigned char* NL = (unsigned char*)(ws + 69 * MB);           // 2 MB
    unsigned char* PG = (unsigned char*)(ws + 71 * MB);           // 2 MB

    // 0) label-match bitmasks (labels only; 16KB inputs stay cache-hot)
    mask_kernel<<<2048, 256, 0, stream>>>(targets_col, targets_row, reward_labels, PL, NL, PG);

    // 1) f32 -> bf16 (both arrays, one launch)
    cvt2_kernel<<<512, 256, 0, stream>>>((const float4*)inputs_col, (const float4*)inputs_row,
                                         (ushort4*)Abf, (ushort4*)Rbf, n * d / 4);

    // 2) sim = col@row^T and gram = col@col^T in one launch
    dim3 ggrid(n / TILE, n / TILE, 2);
    gemm_tile_kernel<<<ggrid, 256, 0, stream>>>(Abf, Rbf, Abf, simbuf, grambuf, m);

    // 3) merged per-row loss + FastAP reward -> contrib[i]
    lossap_kernel<<<n, 256, 0, stream>>>(simbuf, grambuf, PL, NL, PG, contrib, n);

    // 4) final scalar
    final_kernel<<<1, 256, 0, stream>>>(contrib, out, n);
}